// Round 10
// baseline (2795.576 us; speedup 1.0000x reference)
//
#include <hip/hip_runtime.h>
#include <hip/hip_bf16.h>
#include <math.h>

// Problem constants
constexpr int Bn  = 4;
constexpr int Nn  = 10000;
constexpr int En  = 320000;
constexpr int EAn = 80000;
constexpr int OUT_N = 2 * Bn * (EAn / 2);   // 320000 f32: mean | std

// ---------------------------------------------------------------------------
__global__ __launch_bounds__(256) void fill_sentinel(float* out, float v) {
    const int i = blockIdx.x * 256 + threadIdx.x;
    if (i < OUT_N) out[i] = v;
}

// ---------------------------------------------------------------------------
// Index decode (validated r8): int64-vs-int32 autodetect, emit int32.
// ---------------------------------------------------------------------------
__global__ __launch_bounds__(256) void decode_indices(const void* __restrict__ ei_raw,
                                                      const void* __restrict__ mask_raw,
                                                      int* __restrict__ ei32,
                                                      int* __restrict__ mask32) {
    __shared__ int is64;
    if (threadIdx.x == 0) {
        const long long* p = (const long long*)ei_raw;
        int ok = 1;
        for (int i = 0; i < 64; i++) {
            const long long v = p[i];
            if (v < 0 || v >= (long long)Nn) { ok = 0; break; }
        }
        is64 = ok;
    }
    __syncthreads();
    const int idx    = blockIdx.x * 256 + threadIdx.x;
    const int stride = gridDim.x * 256;
    if (is64) {
        for (int i = idx; i < 2 * En; i += stride)
            ei32[i] = (int)((const long long*)ei_raw)[i];
        for (int i = idx; i < EAn; i += stride)
            mask32[i] = (int)((const long long*)mask_raw)[i];
    } else {
        for (int i = idx; i < 2 * En; i += stride)
            ei32[i] = ((const int*)ei_raw)[i];
        for (int i = idx; i < EAn; i += stride)
            mask32[i] = ((const int*)mask_raw)[i];
    }
}

// --------------------------- CSR construction ------------------------------
__global__ __launch_bounds__(256) void count_deg(const int* __restrict__ ei,
                                                 int* __restrict__ degi) {
    const int e = blockIdx.x * 256 + threadIdx.x;
    if (e < En) atomicAdd(&degi[ei[e]], 1);
}

// Exclusive scan over degi -> row_start[0..Nn]. Single block, Hillis-Steele.
__global__ __launch_bounds__(256) void scan_rowstart(const int* __restrict__ degi,
                                                     int* __restrict__ row_start) {
    __shared__ int buf[256];
    __shared__ int carry_s;
    const int tid = threadIdx.x;
    if (tid == 0) { carry_s = 0; row_start[0] = 0; }
    __syncthreads();
    for (int t = 0; t < 40; t++) {             // 40*256 = 10240 >= Nn
        const int i = t * 256 + tid;
        buf[tid] = (i < Nn) ? degi[i] : 0;
        __syncthreads();
        for (int off = 1; off < 256; off <<= 1) {
            const int x = (tid >= off) ? buf[tid - off] : 0;
            __syncthreads();
            buf[tid] += x;
            __syncthreads();
        }
        const int base = carry_s;
        if (i < Nn) row_start[i + 1] = base + buf[tid];
        __syncthreads();
        if (tid == 255) carry_s = base + buf[255];
        __syncthreads();
    }
}

__global__ __launch_bounds__(256) void fill_csr(const int* __restrict__ ei,
                                                const int* __restrict__ row_start,
                                                int* __restrict__ cursor,
                                                int* __restrict__ eid_sorted,
                                                int* __restrict__ s_sorted) {
    const int e = blockIdx.x * 256 + threadIdx.x;
    if (e < En) {
        const int r   = ei[e];
        const int pos = row_start[r] + atomicAdd(&cursor[r], 1);
        eid_sorted[pos] = e;
        s_sorted[pos]   = ei[En + e];
    }
}

// ---------------------------------------------------------------------------
// P = X @ [Wr | Ws] -> (B*N, 256). (validated r2/r9)
// ---------------------------------------------------------------------------
template <int KX>
__global__ __launch_bounds__(256) void precompute_P(const float* __restrict__ X,
                                                    const float* __restrict__ W,
                                                    float* __restrict__ P) {
    __shared__ float xs[16 * KX];
    const int m0  = blockIdx.x * 16;
    const int tid = threadIdx.x;

    for (int idx = tid; idx < 16 * KX; idx += 256)
        xs[idx] = X[(size_t)m0 * KX + idx];
    __syncthreads();

    const int col  = tid;
    const int side = col >> 7;
    const int jj   = col & 127;
    const float* Wp = W + (size_t)(side * KX) * 128 + jj;

    float acc[16];
#pragma unroll
    for (int i = 0; i < 16; i++) acc[i] = 0.f;

    for (int k = 0; k < KX; k++) {
        const float w = Wp[(size_t)k * 128];
#pragma unroll
        for (int i = 0; i < 16; i++) acc[i] += xs[i * KX + k] * w;
    }
#pragma unroll
    for (int i = 0; i < 16; i++) P[(size_t)(m0 + i) * 256 + col] = acc[i];
}

// ---------------------------------------------------------------------------
// CSR node-centric edge aggregation (NO global atomics):
//   block owns receivers [n0, n0+16); walks their CSR edge range in 16-edge
//   chunks; hid = relu(P_r + P_s[s] + ea@We + b1) accumulated in LDS
//   (ds_add_f32); result written ONCE into the recv half of P in place.
// In-place safety: a block writes only its own recv rows (sole reader of
// them), and all cross-block gathers touch the send half (cols 128..256).
// ---------------------------------------------------------------------------
__global__ __launch_bounds__(256) void edge_agg(float* __restrict__ P,
                                                const int* __restrict__ row_start,
                                                const int* __restrict__ eid_sorted,
                                                const int* __restrict__ s_sorted,
                                                const float* __restrict__ edge_attr,
                                                const float* __restrict__ We,  // 16x128
                                                const float* __restrict__ b1) {
    __shared__ float wes[16 * 128];
    __shared__ float agg[16 * 128];
    __shared__ float eas[16 * 16];
    __shared__ int   eidc[16], sc[16], rlc[16];
    __shared__ int   rs_l[17];

    const int b   = blockIdx.y;
    const int n0  = blockIdx.x * 16;
    const int tid = threadIdx.x;

    for (int idx = tid; idx < 16 * 128; idx += 256) {
        wes[idx] = We[idx];
        agg[idx] = 0.f;
    }
    if (tid < 17) rs_l[tid] = row_start[n0 + tid];
    __syncthreads();

    const int beg = rs_l[0], end = rs_l[16];
    const int col = tid & 127, half = tid >> 7;
    const float b1c = b1[col];
    const float* Pb  = P + (size_t)b * Nn * 256;
    const float* eab = edge_attr + (size_t)b * En * 16;

    for (int c0 = beg; c0 < end; c0 += 16) {
        const int cnt = min(16, end - c0);
        if (tid < cnt) {
            const int j = c0 + tid;
            eidc[tid] = eid_sorted[j];
            sc[tid]   = s_sorted[j];
            int lo = 0;
#pragma unroll
            for (int n = 1; n < 16; n++) lo = (j >= rs_l[n]) ? n : lo;
            rlc[tid] = lo;
        }
        __syncthreads();
        {
            const int e = tid >> 4, k = tid & 15;
            if (e < cnt) eas[e * 16 + k] = eab[(size_t)eidc[e] * 16 + k];
        }
        __syncthreads();
#pragma unroll
        for (int i = 0; i < 8; i++) {
            const int e = half * 8 + i;
            if (e < cnt) {
                float a = b1c + Pb[(size_t)(n0 + rlc[e]) * 256 + col]
                              + Pb[(size_t)sc[e] * 256 + 128 + col];
#pragma unroll
                for (int k = 0; k < 16; k++) a += eas[e * 16 + k] * wes[k * 128 + col];
                atomicAdd(&agg[rlc[e] * 128 + col], fmaxf(a, 0.f));
            }
        }
        __syncthreads();
    }

    for (int idx = tid; idx < 16 * 128; idx += 256) {
        const int row = idx >> 7, k = idx & 127;
        P[((size_t)b * Nn + n0 + row) * 256 + k] = agg[idx];
    }
}

// ---------------------------------------------------------------------------
// Fused node: agg2 = aggH@W2 + deg*b2 ; h' = relu([X, agg2]@uw + ub).
// aggH now lives in the recv half of P (stride 256). (structure validated r9)
// ---------------------------------------------------------------------------
template <int KX>
__global__ __launch_bounds__(256) void fused_node(const float* __restrict__ X,
                                                  const float* __restrict__ P,
                                                  const float* __restrict__ W2,
                                                  const float* __restrict__ b2,
                                                  const int* __restrict__ degi,
                                                  const float* __restrict__ uw,
                                                  const float* __restrict__ ub,
                                                  float* Hout) {
    __shared__ float ah[16 * 129];
    __shared__ float ag[16 * 129];
    __shared__ float xs[16 * (KX + 1)];
    __shared__ float dg[16];

    const int m0  = blockIdx.x * 16;     // Nn % 16 == 0 -> never straddles batch
    const int tid = threadIdx.x;

    if (tid < 16) {
        const int row = m0 + tid;
        dg[tid] = (float)degi[row - (row / Nn) * Nn];
    }
    for (int idx = tid; idx < 16 * 128; idx += 256) {
        const int row = idx >> 7, k = idx & 127;
        ah[row * 129 + k] = P[(size_t)(m0 + row) * 256 + k];
    }
    for (int idx = tid; idx < 16 * KX; idx += 256) {
        const int row = idx / KX, k = idx - row * KX;
        xs[row * (KX + 1) + k] = X[(size_t)(m0 + row) * KX + k];
    }
    __syncthreads();

    const int col  = tid & 127;
    const int half = tid >> 7;

    {
        const float b2c = b2[col];
        float acc[8];
#pragma unroll
        for (int i = 0; i < 8; i++) acc[i] = dg[half * 8 + i] * b2c;
#pragma unroll 4
        for (int k = 0; k < 128; k++) {
            const float w = W2[k * 128 + col];
#pragma unroll
            for (int i = 0; i < 8; i++) acc[i] += ah[(half * 8 + i) * 129 + k] * w;
        }
#pragma unroll
        for (int i = 0; i < 8; i++) ag[(half * 8 + i) * 129 + col] = acc[i];
    }
    __syncthreads();

    float acc[8];
#pragma unroll
    for (int i = 0; i < 8; i++) acc[i] = ub[col];
#pragma unroll 4
    for (int k = 0; k < KX; k++) {
        const float w = uw[(size_t)k * 128 + col];
#pragma unroll
        for (int i = 0; i < 8; i++) acc[i] += xs[(half * 8 + i) * (KX + 1) + k] * w;
    }
#pragma unroll 4
    for (int k = 0; k < 128; k++) {
        const float w = uw[(size_t)(KX + k) * 128 + col];
#pragma unroll
        for (int i = 0; i < 8; i++) acc[i] += ag[(half * 8 + i) * 129 + k] * w;
    }
#pragma unroll
    for (int i = 0; i < 8; i++)
        Hout[(size_t)(m0 + half * 8 + i) * 128 + col] = fmaxf(acc[i], 0.f);
}

// ---------------------------------------------------------------------------
// Action head via gathered Pa (validated r9).
// ---------------------------------------------------------------------------
__global__ __launch_bounds__(256) void action_head_gather(const float* __restrict__ Pa,
                                                          const int* __restrict__ ei,
                                                          const float* __restrict__ edge_attr,
                                                          const int* __restrict__ mask,
                                                          const float* __restrict__ aWe,  // 16x128
                                                          const float* __restrict__ b1,
                                                          const float* __restrict__ w2,   // 128x2
                                                          const float* __restrict__ b2,   // 2
                                                          float* __restrict__ act) {
    __shared__ int   ridx[16];
    __shared__ int   sidx[16];
    __shared__ int   eidx[16];
    __shared__ float eas[16 * 17];
    __shared__ float wes[16 * 128];
    __shared__ float hid[16 * 129];

    const int b   = blockIdx.y;
    const int j0  = blockIdx.x * 16;
    const int tid = threadIdx.x;

    if (tid < 16) {
        const int e = mask[j0 + tid];
        eidx[tid]   = e;
        ridx[tid]   = ei[e];
        sidx[tid]   = ei[En + e];
    }
    for (int idx = tid; idx < 16 * 128; idx += 256) wes[idx] = aWe[idx];
    __syncthreads();
    {
        const int e = tid >> 4, k = tid & 15;
        eas[e * 17 + k] = edge_attr[((size_t)b * En + eidx[e]) * 16 + k];
    }
    __syncthreads();

    const int col  = tid & 127;
    const int half = tid >> 7;
    const float bb = b1[col];
#pragma unroll
    for (int i = 0; i < 8; i++) {
        const int e = half * 8 + i;
        float a = bb + Pa[((size_t)b * Nn + ridx[e]) * 256 + col]
                     + Pa[((size_t)b * Nn + sidx[e]) * 256 + 128 + col];
#pragma unroll
        for (int k = 0; k < 16; k++) a += eas[e * 17 + k] * wes[k * 128 + col];
        hid[e * 129 + col] = fmaxf(a, 0.f);
    }
    __syncthreads();

    const int g    = tid >> 4;
    const int lane = tid & 15;
    float o0 = 0.f, o1 = 0.f;
#pragma unroll
    for (int k = lane; k < 128; k += 16) {
        const float hv = hid[g * 129 + k];
        o0 += hv * w2[k * 2 + 0];
        o1 += hv * w2[k * 2 + 1];
    }
#pragma unroll
    for (int m = 8; m >= 1; m >>= 1) {
        o0 += __shfl_xor(o0, m);
        o1 += __shfl_xor(o1, m);
    }
    if (lane == 0) {
        act[((size_t)b * EAn + j0 + g) * 2 + 0] = o0 + b2[0];
        act[((size_t)b * EAn + j0 + g) * 2 + 1] = o1 + b2[1];
    }
}

// ---------------------------------------------------------------------------
// Pair-mean + clip + exp. FLOAT32 output: mean | std. (validated r8)
// ---------------------------------------------------------------------------
__global__ __launch_bounds__(256) void finalize(const float* __restrict__ act,
                                                float* __restrict__ out) {
    const int idx = blockIdx.x * 256 + threadIdx.x;
    constexpr int HALF = EAn / 2;
    if (idx >= Bn * HALF) return;
    const int b = idx / HALF, t = idx - b * HALF;
    const float* a = &act[((size_t)b * EAn + 2 * t) * 2];
    const float m = 0.5f * (a[0] + a[2]);
    float l       = 0.5f * (a[1] + a[3]);
    l = fminf(fmaxf(l, -20.f), 2.f);
    out[idx]             = m;
    out[Bn * HALF + idx] = expf(l);
}

// ---------------------------------------------------------------------------
extern "C" void kernel_launch(void* const* d_in, const int* in_sizes, int n_in,
                              void* d_out, int out_size, void* d_ws, size_t ws_size,
                              hipStream_t stream) {
    (void)out_size;  // unreliable (r6); geometry is compile-time.

    static const long long want[20] = {
        (long long)Bn * Nn * 64, 2LL * En, (long long)Bn * En * 16, (long long)EAn,
        144 * 128, 128, 128 * 128, 128, 192 * 128, 128,
        272 * 128, 128, 128 * 128, 128, 256 * 128, 128,
        272 * 128, 128, 128 * 2, 2};
    bool sig_ok = (n_in == 20);
    if (sig_ok)
        for (int i = 0; i < 20; i++) sig_ok = sig_ok && (in_sizes[i] == want[i]);

    // Workspace (f32/int words):
    //   P | h | ei32 | mk32 | degi | row_start | cursor | eid_sorted | s_sorted
    // act overlays h (dead after last precompute_P). ~67 MB total.
    const size_t PF = (size_t)Bn * Nn * 256;     // 10,240,000
    const size_t hF = (size_t)Bn * Nn * 128;     //  5,120,000
    const size_t needWords = PF + hF + 2 * En + EAn + Nn + (Nn + 16) + Nn + En + En;
    const size_t needBytes = needWords * 4;

    const dim3 blk(256);
    if (!sig_ok) {
        fill_sentinel<<<(OUT_N + 255) / 256, blk, 0, stream>>>((float*)d_out, 5555.f);
        return;
    }
    if (ws_size < needBytes) {
        fill_sentinel<<<(OUT_N + 255) / 256, blk, 0, stream>>>((float*)d_out, 9999.f);
        return;
    }

    const float* nodes  = (const float*)d_in[0];
    const void*  ei_raw = d_in[1];
    const float* eattr  = (const float*)d_in[2];
    const void*  mk_raw = d_in[3];
    const float* g1_mw1 = (const float*)d_in[4];
    const float* g1_mb1 = (const float*)d_in[5];
    const float* g1_mw2 = (const float*)d_in[6];
    const float* g1_mb2 = (const float*)d_in[7];
    const float* g1_uw  = (const float*)d_in[8];
    const float* g1_ub  = (const float*)d_in[9];
    const float* g2_mw1 = (const float*)d_in[10];
    const float* g2_mb1 = (const float*)d_in[11];
    const float* g2_mw2 = (const float*)d_in[12];
    const float* g2_mb2 = (const float*)d_in[13];
    const float* g2_uw  = (const float*)d_in[14];
    const float* g2_ub  = (const float*)d_in[15];
    const float* a_w1   = (const float*)d_in[16];
    const float* a_b1   = (const float*)d_in[17];
    const float* a_w2   = (const float*)d_in[18];
    const float* a_b2   = (const float*)d_in[19];

    float* P     = (float*)d_ws;
    float* h     = P + PF;
    int*   ei32  = (int*)(h + hF);
    int*   mk32  = ei32 + 2 * En;
    int*   degi  = mk32 + EAn;
    int*   rowst = degi + Nn;
    int*   cur   = rowst + (Nn + 16);
    int*   eidS  = cur + Nn;
    int*   sS    = eidS + En;
    float* act   = h;                            // overlay: h dead by head time

    const int  nbNodes = (Bn * Nn) / 16;         // 2500
    const dim3 gAggr(Nn / 16, Bn);               //  625 x 4
    const dim3 gAct(EAn / 16, Bn);               // 5000 x 4

    // ---- Index decode + CSR build (batch-invariant) ----
    decode_indices<<<2500, blk, 0, stream>>>(ei_raw, mk_raw, ei32, mk32);
    hipMemsetAsync(degi, 0, Nn * sizeof(int), stream);
    hipMemsetAsync(cur, 0, Nn * sizeof(int), stream);
    count_deg<<<En / 256, blk, 0, stream>>>(ei32, degi);
    scan_rowstart<<<1, blk, 0, stream>>>(degi, rowst);
    fill_csr<<<En / 256, blk, 0, stream>>>(ei32, rowst, cur, eidS, sS);

    // ---- Layer 1 ----
    precompute_P<64><<<nbNodes, blk, 0, stream>>>(nodes, g1_mw1, P);
    edge_agg<<<gAggr, blk, 0, stream>>>(P, rowst, eidS, sS, eattr,
                                        g1_mw1 + 128 * 128, g1_mb1);
    fused_node<64><<<nbNodes, blk, 0, stream>>>(nodes, P, g1_mw2, g1_mb2, degi,
                                                g1_uw, g1_ub, h);

    // ---- Layer 2 ----
    precompute_P<128><<<nbNodes, blk, 0, stream>>>(h, g2_mw1, P);
    edge_agg<<<gAggr, blk, 0, stream>>>(P, rowst, eidS, sS, eattr,
                                        g2_mw1 + 256 * 128, g2_mb1);
    fused_node<128><<<nbNodes, blk, 0, stream>>>(h, P, g2_mw2, g2_mb2, degi,
                                                 g2_uw, g2_ub, h);

    // ---- Action head ----
    precompute_P<128><<<nbNodes, blk, 0, stream>>>(h, a_w1, P);
    action_head_gather<<<gAct, blk, 0, stream>>>(P, ei32, eattr, mk32,
                                                 a_w1 + 256 * 128, a_b1,
                                                 a_w2, a_b2, act);
    finalize<<<(Bn * (EAn / 2) + 255) / 256, blk, 0, stream>>>(act, (float*)d_out);
}

// Round 11
// 959.842 us; speedup vs baseline: 2.9125x; 2.9125x over previous
//
#include <hip/hip_runtime.h>
#include <hip/hip_bf16.h>
#include <math.h>

// Problem constants
constexpr int Bn  = 4;
constexpr int Nn  = 10000;
constexpr int En  = 320000;
constexpr int EAn = 80000;
constexpr int OUT_N = 2 * Bn * (EAn / 2);   // 320000 f32: mean | std

// ---------------------------------------------------------------------------
__global__ __launch_bounds__(256) void fill_sentinel(float* out, float v) {
    const int i = blockIdx.x * 256 + threadIdx.x;
    if (i < OUT_N) out[i] = v;
}

// ---------------------------------------------------------------------------
// Index decode (validated r8): int64-vs-int32 autodetect, emit int32.
// ---------------------------------------------------------------------------
__global__ __launch_bounds__(256) void decode_indices(const void* __restrict__ ei_raw,
                                                      const void* __restrict__ mask_raw,
                                                      int* __restrict__ ei32,
                                                      int* __restrict__ mask32) {
    __shared__ int is64;
    if (threadIdx.x == 0) {
        const long long* p = (const long long*)ei_raw;
        int ok = 1;
        for (int i = 0; i < 64; i++) {
            const long long v = p[i];
            if (v < 0 || v >= (long long)Nn) { ok = 0; break; }
        }
        is64 = ok;
    }
    __syncthreads();
    const int idx    = blockIdx.x * 256 + threadIdx.x;
    const int stride = gridDim.x * 256;
    if (is64) {
        for (int i = idx; i < 2 * En; i += stride)
            ei32[i] = (int)((const long long*)ei_raw)[i];
        for (int i = idx; i < EAn; i += stride)
            mask32[i] = (int)((const long long*)mask_raw)[i];
    } else {
        for (int i = idx; i < 2 * En; i += stride)
            ei32[i] = ((const int*)ei_raw)[i];
        for (int i = idx; i < EAn; i += stride)
            mask32[i] = ((const int*)mask_raw)[i];
    }
}

// --------------------------- CSR construction (validated r10) ---------------
__global__ __launch_bounds__(256) void count_deg(const int* __restrict__ ei,
                                                 int* __restrict__ degi) {
    const int e = blockIdx.x * 256 + threadIdx.x;
    if (e < En) atomicAdd(&degi[ei[e]], 1);
}

__global__ __launch_bounds__(256) void scan_rowstart(const int* __restrict__ degi,
                                                     int* __restrict__ row_start) {
    __shared__ int buf[256];
    __shared__ int carry_s;
    const int tid = threadIdx.x;
    if (tid == 0) { carry_s = 0; row_start[0] = 0; }
    __syncthreads();
    for (int t = 0; t < 40; t++) {             // 40*256 = 10240 >= Nn
        const int i = t * 256 + tid;
        buf[tid] = (i < Nn) ? degi[i] : 0;
        __syncthreads();
        for (int off = 1; off < 256; off <<= 1) {
            const int x = (tid >= off) ? buf[tid - off] : 0;
            __syncthreads();
            buf[tid] += x;
            __syncthreads();
        }
        const int base = carry_s;
        if (i < Nn) row_start[i + 1] = base + buf[tid];
        __syncthreads();
        if (tid == 255) carry_s = base + buf[255];
        __syncthreads();
    }
}

// rs_sorted[pos] = (r<<16)|s  (both < 2^16); eid_sorted[pos] = original edge id.
__global__ __launch_bounds__(256) void fill_csr(const int* __restrict__ ei,
                                                const int* __restrict__ row_start,
                                                int* __restrict__ cursor,
                                                unsigned int* __restrict__ rs_sorted,
                                                int* __restrict__ eid_sorted) {
    const int e = blockIdx.x * 256 + threadIdx.x;
    if (e < En) {
        const int r   = ei[e];
        const int s   = ei[En + e];
        const int pos = row_start[r] + atomicAdd(&cursor[r], 1);
        rs_sorted[pos]  = ((unsigned int)r << 16) | (unsigned int)s;
        eid_sorted[pos] = e;
    }
}

// ---------------------------------------------------------------------------
// P = X @ [Wr | Ws] -> (B*N, 256). (validated r2/r9)
// ---------------------------------------------------------------------------
template <int KX>
__global__ __launch_bounds__(256) void precompute_P(const float* __restrict__ X,
                                                    const float* __restrict__ W,
                                                    float* __restrict__ P) {
    __shared__ float xs[16 * KX];
    const int m0  = blockIdx.x * 16;
    const int tid = threadIdx.x;

    for (int idx = tid; idx < 16 * KX; idx += 256)
        xs[idx] = X[(size_t)m0 * KX + idx];
    __syncthreads();

    const int col  = tid;
    const int side = col >> 7;
    const int jj   = col & 127;
    const float* Wp = W + (size_t)(side * KX) * 128 + jj;

    float acc[16];
#pragma unroll
    for (int i = 0; i < 16; i++) acc[i] = 0.f;

    for (int k = 0; k < KX; k++) {
        const float w = Wp[(size_t)k * 128];
#pragma unroll
        for (int i = 0; i < 16; i++) acc[i] += xs[i * KX + k] * w;
    }
#pragma unroll
    for (int i = 0; i < 16; i++) P[(size_t)(m0 + i) * 256 + col] = acc[i];
}

// ---------------------------------------------------------------------------
// Edge-parallel scatter over RECEIVER-SORTED edges with register run-length
// reduction: thread's 8 consecutive sorted edges share ~1.2 receivers ->
// one atomicAdd per run (~6-7x fewer atomics than r9), P_r reads L1-broadcast.
// Block: 16 sorted edges x (col 0..127, half); 20000 x 4 blocks (full TLP).
// ---------------------------------------------------------------------------
__global__ __launch_bounds__(256) void edge_scatter_sorted(const float* __restrict__ P,
                                                           const unsigned int* __restrict__ rs_sorted,
                                                           const int* __restrict__ eid_sorted,
                                                           const float* __restrict__ edge_attr,
                                                           const float* __restrict__ We,  // 16x128
                                                           const float* __restrict__ b1,
                                                           float* __restrict__ aggH) {
    __shared__ int   rc[16], sc[16], ec[16];
    __shared__ float eas[16 * 16];
    __shared__ float wes[16 * 128];

    const int b   = blockIdx.y;
    const int e0  = blockIdx.x * 16;
    const int tid = threadIdx.x;

    if (tid < 16) {
        const unsigned int v = rs_sorted[e0 + tid];
        rc[tid] = (int)(v >> 16);
        sc[tid] = (int)(v & 0xffffu);
        ec[tid] = eid_sorted[e0 + tid];
    }
    for (int idx = tid; idx < 16 * 128; idx += 256) wes[idx] = We[idx];
    __syncthreads();
    {
        const int e = tid >> 4, k = tid & 15;
        eas[e * 16 + k] = edge_attr[((size_t)b * En + ec[e]) * 16 + k];
    }
    __syncthreads();

    const int col  = tid & 127;
    const int half = tid >> 7;
    const float b1c = b1[col];
    const float* Pb   = P + (size_t)b * Nn * 256;
    float*       aggb = aggH + (size_t)b * Nn * 128;

    float run  = 0.f;
    int   curR = rc[half * 8];
#pragma unroll
    for (int i = 0; i < 8; i++) {
        const int e = half * 8 + i;
        const int r = rc[e];
        float a = b1c + Pb[(size_t)r * 256 + col]
                      + Pb[(size_t)sc[e] * 256 + 128 + col];
#pragma unroll
        for (int k = 0; k < 16; k++) a += eas[e * 16 + k] * wes[k * 128 + col];
        const float v = fmaxf(a, 0.f);
        if (r != curR) {
            atomicAdd(&aggb[(size_t)curR * 128 + col], run);
            run = 0.f;
            curR = r;
        }
        run += v;
    }
    atomicAdd(&aggb[(size_t)curR * 128 + col], run);
}

// ---------------------------------------------------------------------------
// Fused node: agg2 = aggH@W2 + deg*b2 ; h' = relu([X, agg2]@uw + ub).
// deg derived from row_start diffs. In-place safe (LDS staging first).
// ---------------------------------------------------------------------------
template <int KX>
__global__ __launch_bounds__(256) void fused_node(const float* __restrict__ X,
                                                  const float* __restrict__ aggH,
                                                  const float* __restrict__ W2,
                                                  const float* __restrict__ b2,
                                                  const int* __restrict__ row_start,
                                                  const float* __restrict__ uw,
                                                  const float* __restrict__ ub,
                                                  float* Hout) {
    __shared__ float ah[16 * 129];
    __shared__ float ag[16 * 129];
    __shared__ float xs[16 * (KX + 1)];
    __shared__ float dg[16];

    const int m0  = blockIdx.x * 16;     // Nn % 16 == 0 -> never straddles batch
    const int tid = threadIdx.x;

    if (tid < 16) {
        const int row = m0 + tid;
        const int nl  = row - (row / Nn) * Nn;
        dg[tid] = (float)(row_start[nl + 1] - row_start[nl]);
    }
    for (int idx = tid; idx < 16 * 128; idx += 256) {
        const int row = idx >> 7, k = idx & 127;
        ah[row * 129 + k] = aggH[(size_t)(m0 + row) * 128 + k];
    }
    for (int idx = tid; idx < 16 * KX; idx += 256) {
        const int row = idx / KX, k = idx - row * KX;
        xs[row * (KX + 1) + k] = X[(size_t)(m0 + row) * KX + k];
    }
    __syncthreads();

    const int col  = tid & 127;
    const int half = tid >> 7;

    {
        const float b2c = b2[col];
        float acc[8];
#pragma unroll
        for (int i = 0; i < 8; i++) acc[i] = dg[half * 8 + i] * b2c;
#pragma unroll 4
        for (int k = 0; k < 128; k++) {
            const float w = W2[k * 128 + col];
#pragma unroll
            for (int i = 0; i < 8; i++) acc[i] += ah[(half * 8 + i) * 129 + k] * w;
        }
#pragma unroll
        for (int i = 0; i < 8; i++) ag[(half * 8 + i) * 129 + col] = acc[i];
    }
    __syncthreads();

    float acc[8];
#pragma unroll
    for (int i = 0; i < 8; i++) acc[i] = ub[col];
#pragma unroll 4
    for (int k = 0; k < KX; k++) {
        const float w = uw[(size_t)k * 128 + col];
#pragma unroll
        for (int i = 0; i < 8; i++) acc[i] += xs[(half * 8 + i) * (KX + 1) + k] * w;
    }
#pragma unroll 4
    for (int k = 0; k < 128; k++) {
        const float w = uw[(size_t)(KX + k) * 128 + col];
#pragma unroll
        for (int i = 0; i < 8; i++) acc[i] += ag[(half * 8 + i) * 129 + k] * w;
    }
#pragma unroll
    for (int i = 0; i < 8; i++)
        Hout[(size_t)(m0 + half * 8 + i) * 128 + col] = fmaxf(acc[i], 0.f);
}

// ---------------------------------------------------------------------------
// Action head via gathered Pa (validated r9).
// ---------------------------------------------------------------------------
__global__ __launch_bounds__(256) void action_head_gather(const float* __restrict__ Pa,
                                                          const int* __restrict__ ei,
                                                          const float* __restrict__ edge_attr,
                                                          const int* __restrict__ mask,
                                                          const float* __restrict__ aWe,  // 16x128
                                                          const float* __restrict__ b1,
                                                          const float* __restrict__ w2,   // 128x2
                                                          const float* __restrict__ b2,   // 2
                                                          float* __restrict__ act) {
    __shared__ int   ridx[16];
    __shared__ int   sidx[16];
    __shared__ int   eidx[16];
    __shared__ float eas[16 * 17];
    __shared__ float wes[16 * 128];
    __shared__ float hid[16 * 129];

    const int b   = blockIdx.y;
    const int j0  = blockIdx.x * 16;
    const int tid = threadIdx.x;

    if (tid < 16) {
        const int e = mask[j0 + tid];
        eidx[tid]   = e;
        ridx[tid]   = ei[e];
        sidx[tid]   = ei[En + e];
    }
    for (int idx = tid; idx < 16 * 128; idx += 256) wes[idx] = aWe[idx];
    __syncthreads();
    {
        const int e = tid >> 4, k = tid & 15;
        eas[e * 17 + k] = edge_attr[((size_t)b * En + eidx[e]) * 16 + k];
    }
    __syncthreads();

    const int col  = tid & 127;
    const int half = tid >> 7;
    const float bb = b1[col];
#pragma unroll
    for (int i = 0; i < 8; i++) {
        const int e = half * 8 + i;
        float a = bb + Pa[((size_t)b * Nn + ridx[e]) * 256 + col]
                     + Pa[((size_t)b * Nn + sidx[e]) * 256 + 128 + col];
#pragma unroll
        for (int k = 0; k < 16; k++) a += eas[e * 17 + k] * wes[k * 128 + col];
        hid[e * 129 + col] = fmaxf(a, 0.f);
    }
    __syncthreads();

    const int g    = tid >> 4;
    const int lane = tid & 15;
    float o0 = 0.f, o1 = 0.f;
#pragma unroll
    for (int k = lane; k < 128; k += 16) {
        const float hv = hid[g * 129 + k];
        o0 += hv * w2[k * 2 + 0];
        o1 += hv * w2[k * 2 + 1];
    }
#pragma unroll
    for (int m = 8; m >= 1; m >>= 1) {
        o0 += __shfl_xor(o0, m);
        o1 += __shfl_xor(o1, m);
    }
    if (lane == 0) {
        act[((size_t)b * EAn + j0 + g) * 2 + 0] = o0 + b2[0];
        act[((size_t)b * EAn + j0 + g) * 2 + 1] = o1 + b2[1];
    }
}

// ---------------------------------------------------------------------------
// Pair-mean + clip + exp. FLOAT32 output: mean | std. (validated r8)
// ---------------------------------------------------------------------------
__global__ __launch_bounds__(256) void finalize(const float* __restrict__ act,
                                                float* __restrict__ out) {
    const int idx = blockIdx.x * 256 + threadIdx.x;
    constexpr int HALF = EAn / 2;
    if (idx >= Bn * HALF) return;
    const int b = idx / HALF, t = idx - b * HALF;
    const float* a = &act[((size_t)b * EAn + 2 * t) * 2];
    const float m = 0.5f * (a[0] + a[2]);
    float l       = 0.5f * (a[1] + a[3]);
    l = fminf(fmaxf(l, -20.f), 2.f);
    out[idx]             = m;
    out[Bn * HALF + idx] = expf(l);
}

// ---------------------------------------------------------------------------
extern "C" void kernel_launch(void* const* d_in, const int* in_sizes, int n_in,
                              void* d_out, int out_size, void* d_ws, size_t ws_size,
                              hipStream_t stream) {
    (void)out_size;  // unreliable (r6); geometry is compile-time.

    static const long long want[20] = {
        (long long)Bn * Nn * 64, 2LL * En, (long long)Bn * En * 16, (long long)EAn,
        144 * 128, 128, 128 * 128, 128, 192 * 128, 128,
        272 * 128, 128, 128 * 128, 128, 256 * 128, 128,
        272 * 128, 128, 128 * 2, 2};
    bool sig_ok = (n_in == 20);
    if (sig_ok)
        for (int i = 0; i < 20; i++) sig_ok = sig_ok && (in_sizes[i] == want[i]);

    // Workspace (words): P | aggH | h | ei32 | mk32 | rowst | rsS | eidS
    //   degi+cur live inside h (dead during CSR build); act overlays h later.
    const size_t PF   = (size_t)Bn * Nn * 256;   // 10,240,000
    const size_t aggF = (size_t)Bn * Nn * 128;   //  5,120,000
    const size_t hF   = (size_t)Bn * Nn * 128;   //  5,120,000
    const size_t needWords = PF + aggF + hF + 2 * En + EAn + (Nn + 16) + En + En;
    const size_t needBytes = needWords * 4;      // ~87.4 MB

    const dim3 blk(256);
    if (!sig_ok) {
        fill_sentinel<<<(OUT_N + 255) / 256, blk, 0, stream>>>((float*)d_out, 5555.f);
        return;
    }
    if (ws_size < needBytes) {
        fill_sentinel<<<(OUT_N + 255) / 256, blk, 0, stream>>>((float*)d_out, 9999.f);
        return;
    }

    const float* nodes  = (const float*)d_in[0];
    const void*  ei_raw = d_in[1];
    const float* eattr  = (const float*)d_in[2];
    const void*  mk_raw = d_in[3];
    const float* g1_mw1 = (const float*)d_in[4];
    const float* g1_mb1 = (const float*)d_in[5];
    const float* g1_mw2 = (const float*)d_in[6];
    const float* g1_mb2 = (const float*)d_in[7];
    const float* g1_uw  = (const float*)d_in[8];
    const float* g1_ub  = (const float*)d_in[9];
    const float* g2_mw1 = (const float*)d_in[10];
    const float* g2_mb1 = (const float*)d_in[11];
    const float* g2_mw2 = (const float*)d_in[12];
    const float* g2_mb2 = (const float*)d_in[13];
    const float* g2_uw  = (const float*)d_in[14];
    const float* g2_ub  = (const float*)d_in[15];
    const float* a_w1   = (const float*)d_in[16];
    const float* a_b1   = (const float*)d_in[17];
    const float* a_w2   = (const float*)d_in[18];
    const float* a_b2   = (const float*)d_in[19];

    float*        P     = (float*)d_ws;
    float*        aggH  = P + PF;
    float*        h     = aggH + aggF;
    int*          ei32  = (int*)(h + hF);
    int*          mk32  = ei32 + 2 * En;
    int*          rowst = mk32 + EAn;
    unsigned int* rsS   = (unsigned int*)(rowst + (Nn + 16));
    int*          eidS  = (int*)(rsS + En);
    // CSR-build temporaries inside h (dead until fused_node layer 1):
    int*   degi = (int*)h;
    int*   cur  = degi + Nn;
    float* act  = h;                             // overlay: h dead by head time

    const int  nbNodes = (Bn * Nn) / 16;         // 2500
    const dim3 gEdge(En / 16, Bn);               // 20000 x 4
    const dim3 gAct(EAn / 16, Bn);               //  5000 x 4
    const size_t aggBytes = aggF * 4;

    // ---- Index decode + CSR build (batch-invariant) ----
    decode_indices<<<2500, blk, 0, stream>>>(ei_raw, mk_raw, ei32, mk32);
    hipMemsetAsync(degi, 0, Nn * sizeof(int), stream);
    hipMemsetAsync(cur, 0, Nn * sizeof(int), stream);
    count_deg<<<En / 256, blk, 0, stream>>>(ei32, degi);
    scan_rowstart<<<1, blk, 0, stream>>>(degi, rowst);
    fill_csr<<<En / 256, blk, 0, stream>>>(ei32, rowst, cur, rsS, eidS);

    // ---- Layer 1 ----
    precompute_P<64><<<nbNodes, blk, 0, stream>>>(nodes, g1_mw1, P);
    hipMemsetAsync(aggH, 0, aggBytes, stream);
    edge_scatter_sorted<<<gEdge, blk, 0, stream>>>(P, rsS, eidS, eattr,
                                                   g1_mw1 + 128 * 128, g1_mb1, aggH);
    fused_node<64><<<nbNodes, blk, 0, stream>>>(nodes, aggH, g1_mw2, g1_mb2, rowst,
                                                g1_uw, g1_ub, h);

    // ---- Layer 2 ----
    precompute_P<128><<<nbNodes, blk, 0, stream>>>(h, g2_mw1, P);
    hipMemsetAsync(aggH, 0, aggBytes, stream);
    edge_scatter_sorted<<<gEdge, blk, 0, stream>>>(P, rsS, eidS, eattr,
                                                   g2_mw1 + 256 * 128, g2_mb1, aggH);
    fused_node<128><<<nbNodes, blk, 0, stream>>>(h, aggH, g2_mw2, g2_mb2, rowst,
                                                 g2_uw, g2_ub, h);

    // ---- Action head ----
    precompute_P<128><<<nbNodes, blk, 0, stream>>>(h, a_w1, P);
    action_head_gather<<<gAct, blk, 0, stream>>>(P, ei32, eattr, mk32,
                                                 a_w1 + 256 * 128, a_b1,
                                                 a_w2, a_b2, act);
    finalize<<<(Bn * (EAn / 2) + 255) / 256, blk, 0, stream>>>(act, (float*)d_out);
}